// Round 10
// baseline (499.624 us; speedup 1.0000x reference)
//
#include <hip/hip_runtime.h>
#include <math.h>

#define MTOT 42000
#define NB 8
#define NCLS 80
#define CAP_LIST 4096
#define MAXT 256
#define NT_MAX 2048
#define NBLK 256          // persistent grid: 256 blocks (=CU count) x 256 threads
#define KMAX 6            // ceil(165/32) column-block iterations per block
#define GX_MAIN 165       // 256-wide column blocks per image
#define NCH 32            // bestprior chunks
#define CS 1313           // ceil(42000/32)

// ---- workspace byte offsets ----
#define O_OVR 0
#define O_GIX (O_OVR + NB*MTOT*4)
#define O_LST (O_GIX + NB*MTOT*4)
#define O_LJ  (O_LST + NB*MAXT*4)
#define O_CNT (O_LJ + NT_MAX*4)
#define O_BPP (O_CNT + 64)                 // u64 partials [NT_MAX][NCH] (8-aligned)
#define O_PA  (O_BPP + NT_MAX*NCH*8)       // float4 partials [NBLK] (16-aligned)
#define O_PN  (O_PA + NBLK*16)
#define O_P2  (O_PN + NBLK*4)
#define O_BINL (O_P2 + NBLK*8)             // tie list [NB][CAP_LIST][3] (u,gid,bce)
#define O_ACC (O_BINL + NB*CAP_LIST*3*4)
#define O_ACCI (O_ACC + 64)
#define O_HA  (O_ACCI + 128)               // coarse hist [NB][256]
#define O_HB  (O_HA + NB*256*4)            // fine hist [NB][256]
#define O_BAR (O_HB + NB*256*4)            // 8 barrier counters
// accf: [0]=sum_xy [1]=sum_wh [2]=sum_ce [3]=sum_bce_pos
// acci: [0]=num_pos [2..9]=ca->bs16 [10..17]=kres->r [18..25]=tie listn

__device__ __forceinline__ float iou_cxcywh(float acx,float acy,float aw,float ah,
                                            float bcx,float bcy,float bw,float bh){
  float ax0=acx-aw*0.5f, ay0=acy-ah*0.5f, ax1=acx+aw*0.5f, ay1=acy+ah*0.5f;
  float bx0=bcx-bw*0.5f, by0=bcy-bh*0.5f, bx1=bcx+bw*0.5f, by1=bcy+bh*0.5f;
  float tlx=fmaxf(ax0,bx0), tly=fmaxf(ay0,by0);
  float brx=fminf(ax1,bx1), bry=fminf(ay1,by1);
  float wx=fmaxf(brx-tlx,0.f), wy=fmaxf(bry-tly,0.f);
  float inter=wx*wy;
  return inter/(aw*ah+bw*bh-inter+1e-9f);
}

__device__ __forceinline__ float sl1(float x){
  float ax=fabsf(x); return ax<1.f ? 0.5f*ax*ax : ax-0.5f;
}

__device__ __forceinline__ void feat_base(const float* f0,const float* f1,const float* f2,
                                          int i,int m,const float** basep,int* hwp){
  const float* fp; int hw, loc;
  if(m<32000){ fp=f0; hw=6400; loc=m; }
  else if(m<40000){ fp=f1; hw=1600; loc=m-32000; }
  else { fp=f2; hw=400; loc=m-40000; }
  int a=loc/hw, p=loc-a*hw;
  *basep = fp + (size_t)(i*425 + a*85)*(size_t)hw + p;
  *hwp = hw;
}

// software grid barrier: per-phase counter (zeroed by k_init0 each call)
__device__ __forceinline__ void gbar(int* ctr){
  __syncthreads();
  if(threadIdx.x==0){
    __threadfence();
    __hip_atomic_fetch_add(ctr,1,__ATOMIC_ACQ_REL,__HIP_MEMORY_SCOPE_AGENT);
    while(__hip_atomic_load(ctr,__ATOMIC_ACQUIRE,__HIP_MEMORY_SCOPE_AGENT)<NBLK)
      __builtin_amdgcn_s_sleep(4);
    __threadfence();
  }
  __syncthreads();
}

__global__ void k_init0(int* bars){
  if(threadIdx.x<8) bars[threadIdx.x]=0;
}

// inline fine-scan: 16-bit boundary bin + residual
__device__ __forceinline__ void fine_scan(const unsigned* hb,int ca,int kres,int* bs_out,int* r_out){
  if(ca==0x7fffffff){ *bs_out=0x7fffffff; *r_out=0; return; }
  int run=0, bs=-1, r=0;
  for(int f=255;f>=0;f--){
    int cb=(int)hb[f];
    if(run<kres && run+cb>=kres){ bs=(ca<<8)|f; r=kres-run; break; }
    run+=cb;
  }
  if(bs<0){ bs=(ca<<8); r=kres-run; }
  *bs_out=bs; *r_out=r;
}

__global__ void __launch_bounds__(256,1) k_mega(
    const float* __restrict__ f0,const float* __restrict__ f1,const float* __restrict__ f2,
    const float* __restrict__ tg,const float* __restrict__ priors,
    int nt, char* __restrict__ ws, float* __restrict__ out)
{
  float* ovr=(float*)(ws+O_OVR);
  int* gix=(int*)(ws+O_GIX);
  int* list=(int*)(ws+O_LST);
  int* lj=(int*)(ws+O_LJ);
  int* cnt=(int*)(ws+O_CNT);
  unsigned long long* bpp=(unsigned long long*)(ws+O_BPP);
  float4* partA=(float4*)(ws+O_PA);
  int* partN=(int*)(ws+O_PN);
  float2* part2=(float2*)(ws+O_P2);
  int* binlist=(int*)(ws+O_BINL);
  float* accf=(float*)(ws+O_ACC);
  int* acci=(int*)(ws+O_ACCI);
  unsigned* histA=(unsigned*)(ws+O_HA);
  unsigned* histB=(unsigned*)(ws+O_HB);
  int* bars=(int*)(ws+O_BAR);

  int b=blockIdx.x, tid=threadIdx.x;
  int lane=tid&63, wid=tid>>6;
  int i_img=b>>5, cb0=b&31;       // 32 blocks per image; cols cb0+32k

  __shared__ __align__(16) float st[MAXT*6];
  __shared__ int sidx[MAXT];
  __shared__ unsigned long long su[256];
  __shared__ unsigned h[256];
  __shared__ int tbp[NT_MAX];
  __shared__ int timg[NT_MAX];
  __shared__ float rA[4],rB[4],rC[4],rD[4];
  __shared__ int rN[4];

  // ---------------- P0: zero hists/tie-counters + target prep ----------------
  {
    int g=b*256+tid;
    if(g<NB*256) histA[g]=0u;
    else if(g<2*NB*256) histB[g-NB*256]=0u;
    else if(g<2*NB*256+NB) acci[18+(g-2*NB*256)]=0;
    if(g<nt){
      int img=(int)tg[g*6];
      int j=0;
      for(int q=0;q<g;q++) if((int)tg[q*6]==img) j++;
      lj[g]=j;
      if(img>=0&&img<NB&&j<MAXT) list[img*MAXT+j]=g;
    }
    if(g>=NBLK*256-NB){
      int im=g-(NBLK*256-NB);
      int c=0;
      for(int q=0;q<nt;q++) if((int)tg[q*6]==im) c++;
      cnt[im]=c;
    }
  }
  gbar(&bars[0]);

  // ---------------- P1: match (own image/cols) + bpA partials ----------------
  {
    int n=min(max(cnt[i_img],0),MAXT);
    for(int j=tid;j<n;j+=256){
      int t=list[i_img*MAXT+j];
      t=min(max(t,0),nt-1);
      sidx[j]=t;
      #pragma unroll
      for(int q=0;q<6;q++) st[j*6+q]=tg[t*6+q];
    }
    __syncthreads();
    for(int k=0;k<KMAX;k++){
      int cb=cb0+32*k;
      if(cb>=GX_MAIN) break;
      int m=cb*256+tid;
      if(m<MTOT){
        float4 pr=((const float4*)priors)[m];
        float maxv=-1.f; int bi=0;
        for(int j=0;j<n;j++){
          float v=iou_cxcywh(st[j*6+2],st[j*6+3],st[j*6+4],st[j*6+5],pr.x,pr.y,pr.z,pr.w);
          if(v>maxv){ maxv=v; bi=sidx[j]; }
        }
        ovr[i_img*MTOT+m]=maxv; gix[i_img*MTOT+m]=bi;
      }
    }
    __syncthreads();
    int nvb=nt*NCH;
    int niter=(nvb+NBLK-1)/NBLK;
    for(int q=0;q<niter;q++){
      int vb=b+NBLK*q;
      bool act=(vb<nvb);
      unsigned long long p=0ull;
      if(act){
        int t=vb/NCH, c=vb-(vb/NCH)*NCH;
        float acx=tg[t*6+2],acy=tg[t*6+3],aw=tg[t*6+4],ah=tg[t*6+5];
        int m0=c*CS, m1=min(m0+CS,MTOT);
        float bv=-1.f; int bm=0;
        for(int m=m0+tid;m<m1;m+=256){
          float4 pr=((const float4*)priors)[m];
          float v=iou_cxcywh(acx,acy,aw,ah,pr.x,pr.y,pr.z,pr.w);
          if(v>bv){ bv=v; bm=m; }
        }
        p=(bv<0.f)?0ull:(((unsigned long long)__float_as_uint(bv))<<32)|(unsigned)(~bm);
      }
      su[tid]=p;
      __syncthreads();
      for(int o=128;o>0;o>>=1){
        if(tid<o){ if(su[tid+o]>su[tid]) su[tid]=su[tid+o]; }
        __syncthreads();
      }
      if(act&&tid==0){ int t=vb/NCH, c=vb-(vb/NCH)*NCH; bpp[(size_t)t*NCH+c]=su[0]; }
      __syncthreads();
    }
  }
  gbar(&bars[1]);

  // ---------------- P2: bpB + forced-prior scatter (block 0) ----------------
  if(b==0){
    for(int t=tid;t<nt;t+=256){
      unsigned long long best=0ull;
      const unsigned long long* pp=&bpp[(size_t)t*NCH];
      for(int c=0;c<NCH;c++){ unsigned long long v=pp[c]; if(v>best) best=v; }
      int bm=~((unsigned)(best&0xFFFFFFFFull));
      tbp[t]=min(max(bm,0),MTOT-1);
      timg[t]=(int)tg[t*6];
    }
    __syncthreads();
    for(int t=tid;t<nt;t+=256){
      int img=timg[t];
      if(img<0||img>=NB) continue;
      int myp=tbp[t];
      bool last=true;
      for(int q=t+1;q<nt;q++) if(timg[q]==img&&tbp[q]==myp){ last=false; break; }
      if(last) ovr[img*MTOT+myp]=(float)lj[t];
    }
  }
  gbar(&bars[2]);

  // ---------------- P3: loss main (lc/bce kept in registers) ----------------
  float lcv[KMAX], bcev[KMAX];
  unsigned validb=0;
  {
    float lxy=0.f,lwh=0.f,bcep=0.f,wce=0.f; int npos=0;
    h[tid]=0u;
    __syncthreads();
    #pragma unroll
    for(int k=0;k<KMAX;k++){
      int cb=cb0+32*k;
      int m=cb*256+tid;
      bool valid=(cb<GX_MAIN)&&(m<MTOT);
      float lc=0.f,bce=0.f; bool pos=false; int gi=0;
      if(valid){
        int gid=i_img*MTOT+m;
        const float* base; int hw;
        feat_base(f0,f1,f2,i_img,m,&base,&hw);
        float ov=ovr[gid];
        gi=min(max(gix[gid],0),nt-1);
        float tc=tg[gi*6+1]+1.f;
        pos=(ov>=0.5f)&&(tc>0.f);
        float obj=base[(size_t)4*hw];
        float sp=log1pf(expf(-fabsf(obj)));
        bce=fmaxf(obj,0.f)-(pos?obj:0.f)+sp;
        lc=pos?0.f:(fmaxf(-obj,0.f)+sp);
        atomicAdd(&h[__float_as_uint(lc)>>24],1u);
        if(pos){
          npos++; bcep+=bce;
          float4 pr=((const float4*)priors)[m];
          float bx=tg[gi*6+2],by=tg[gi*6+3],bw=tg[gi*6+4],bh=tg[gi*6+5];
          float tx=(bx-pr.x)/pr.z, ty=(by-pr.y)/pr.w;
          float tw=logf(bw/pr.z), th=logf(bh/pr.w);
          lxy+=sl1(base[0]-tx)+sl1(base[(size_t)hw]-ty);
          lwh+=sl1(base[(size_t)2*hw]-tw)+sl1(base[(size_t)3*hw]-th);
        }
      }
      lcv[k]=lc; bcev[k]=bce;
      validb|=(valid?1u:0u)<<k;
      // wave-cooperative CE for this k
      int m_cur=m;
      unsigned long long mask=__ballot(valid&&pos);
      while(mask){
        int s=__ffsll((unsigned long long)mask)-1;
        mask&=mask-1;
        int m_s=__shfl(m_cur,s);
        int gi_s=__shfl(gi,s);
        const float* bs2; int hws;
        feat_base(f0,f1,f2,i_img,m_s,&bs2,&hws);
        int label=(int)(tg[gi_s*6+1]+1.f)-1;
        label=min(NCLS-1,max(0,label));
        float v0=bs2[(size_t)(5+lane)*hws];
        float v1=(lane<16)?bs2[(size_t)(69+lane)*hws]:-3.0e38f;
        float mx=fmaxf(v0,v1);
        #pragma unroll
        for(int o=32;o>0;o>>=1) mx=fmaxf(mx,__shfl_xor(mx,o));
        float se=expf(v0-mx)+((lane<16)?expf(v1-mx):0.f);
        float xl=((lane==label)?v0:0.f)+((lane<16&&lane+64==label)?v1:0.f);
        #pragma unroll
        for(int o=32;o>0;o>>=1){ se+=__shfl_xor(se,o); xl+=__shfl_xor(xl,o); }
        wce+=logf(se)+mx-xl;     // identical on all lanes
      }
    }
    #pragma unroll
    for(int o=32;o>0;o>>=1){
      lxy+=__shfl_xor(lxy,o); lwh+=__shfl_xor(lwh,o);
      bcep+=__shfl_xor(bcep,o); npos+=__shfl_xor(npos,o);
    }
    if(lane==0){ rA[wid]=lxy; rB[wid]=lwh; rC[wid]=wce; rD[wid]=bcep; rN[wid]=npos; }
    __syncthreads();
    unsigned hc=h[tid];
    if(hc) atomicAdd(&histA[i_img*256+tid],hc);
    if(tid==0){
      partA[b]=make_float4(rA[0]+rA[1]+rA[2]+rA[3], rB[0]+rB[1]+rB[2]+rB[3],
                           rC[0]+rC[1]+rC[2]+rC[3], rD[0]+rD[1]+rD[2]+rD[3]);
      partN[b]=rN[0]+rN[1]+rN[2]+rN[3];
    }
  }
  gbar(&bars[3]);

  // ---------------- P4: np reduce + coarse scan (blocks 0..7) ----------------
  if(b<NB){
    int* an=(int*)sidx;
    an[tid]=partN[tid];
    __syncthreads();
    for(int o=128;o>0;o>>=1){ if(tid<o) an[tid]+=an[tid+o]; __syncthreads(); }
    int np=an[0];
    if(b==0){
      float4* fr=(float4*)st;
      fr[tid]=partA[tid];
      __syncthreads();
      for(int o=128;o>0;o>>=1){
        if(tid<o){
          fr[tid].x+=fr[tid+o].x; fr[tid].y+=fr[tid+o].y;
          fr[tid].z+=fr[tid+o].z; fr[tid].w+=fr[tid+o].w;
        }
        __syncthreads();
      }
      if(tid==0){ accf[0]=fr[0].x; accf[1]=fr[0].y; accf[2]=fr[0].z; accf[3]=fr[0].w; acci[0]=np; }
    }
    h[tid]=histA[b*256+tid];
    __syncthreads();
    if(tid==0){
      int kk=min(np,MTOT-np);
      if(kk<=0){ acci[2+b]=0x7fffffff; acci[10+b]=0; }
      else{
        int run=0, ca=-1, kres=0;
        for(int c2=255;c2>=0;c2--){
          int cbn=(int)h[c2];
          if(run<kk&&run+cbn>=kk){ ca=c2; kres=kk-run; break; }
          run+=cbn;
        }
        if(ca<0){ ca=0; kres=kk-run; }
        acci[2+b]=ca; acci[10+b]=kres;
      }
    }
  }
  gbar(&bars[4]);

  // ---------------- P5a: fine hist from registers ----------------
  {
    int ca=acci[2+i_img];
    if(ca!=0x7fffffff){
      #pragma unroll
      for(int k=0;k<KMAX;k++){
        if(validb&(1u<<k)){
          unsigned u=__float_as_uint(lcv[k]);
          if((int)(u>>24)==ca) atomicAdd(&histB[i_img*256+((u>>16)&0xFF)],1u);
        }
      }
    }
  }
  gbar(&bars[5]);

  // ---------------- P5b: fine scan (blocks 0..7) ----------------
  if(b<NB){
    int ca=acci[2+b], kres=acci[10+b];
    h[tid]=(ca==0x7fffffff)?0u:histB[b*256+tid];
    __syncthreads();
    if(tid==0){
      int bs,r; fine_scan(h,ca,kres,&bs,&r);
      acci[2+b]=bs; acci[10+b]=r;
    }
  }
  gbar(&bars[6]);

  // ---------------- P5c: select from registers + tie list ----------------
  {
    int bs_=acci[2+i_img];
    float s=0.f,c=0.f;
    #pragma unroll
    for(int k=0;k<KMAX;k++){
      if(validb&(1u<<k)){
        unsigned u=__float_as_uint(lcv[k]);
        int bin=(int)(u>>16);
        if(bin>bs_){ s+=bcev[k]; c+=1.f; }
        else if(bin==bs_){
          int idx=atomicAdd(&acci[18+i_img],1);
          if(idx<CAP_LIST){
            int gid=i_img*MTOT+(cb0+32*k)*256+tid;
            binlist[((size_t)i_img*CAP_LIST+idx)*3  ]=(int)u;
            binlist[((size_t)i_img*CAP_LIST+idx)*3+1]=gid;
            binlist[((size_t)i_img*CAP_LIST+idx)*3+2]=__float_as_int(bcev[k]);
          }
        }
      }
    }
    #pragma unroll
    for(int o=32;o>0;o>>=1){ s+=__shfl_xor(s,o); c+=__shfl_xor(c,o); }
    if(lane==0){ rA[wid]=s; rB[wid]=c; }
    __syncthreads();
    if(tid==0) part2[b]=make_float2(rA[0]+rA[1]+rA[2]+rA[3], rB[0]+rB[1]+rB[2]+rB[3]);
  }
  gbar(&bars[7]);

  // ---------------- P6: block 0 — reduce partials, ties, final ----------------
  if(b==0){
    float* fs=st; float* fc=st+256;
    float2 p2=part2[tid];
    fs[tid]=p2.x; fc[tid]=p2.y;
    __syncthreads();
    for(int o=128;o>0;o>>=1){
      if(tid<o){ fs[tid]+=fs[tid+o]; fc[tid]+=fc[tid+o]; }
      __syncthreads();
    }
    float negsum=fs[0], negcnt=fc[0];
    __syncthreads();
    float tsum=0.f; int tcnt=0;
    for(int i=0;i<NB;i++){
      int bs=acci[2+i];
      if(bs==0x7fffffff) continue;
      int n=min(acci[18+i],CAP_LIST);
      int r=acci[10+i];
      for(int e=tid;e<n;e+=256){
        const int* be=&binlist[((size_t)i*CAP_LIST+e)*3];
        unsigned ue=(unsigned)be[0]; int ge=be[1];
        int rank=0;
        for(int q=0;q<n;q++){
          const int* bq=&binlist[((size_t)i*CAP_LIST+q)*3];
          unsigned uq=(unsigned)bq[0]; int gq=bq[1];
          rank += ((uq>ue)||(uq==ue&&gq<ge))?1:0;
        }
        if(rank<r){ tsum+=__int_as_float(be[2]); tcnt++; }
      }
    }
    float ftc=(float)tcnt;
    #pragma unroll
    for(int o=32;o>0;o>>=1){ tsum+=__shfl_xor(tsum,o); ftc+=__shfl_xor(ftc,o); }
    if(lane==0){ rA[wid]=tsum; rB[wid]=ftc; }
    __syncthreads();
    if(tid==0){
      negsum+=rA[0]+rA[1]+rA[2]+rA[3];
      negcnt+=rB[0]+rB[1]+rB[2]+rB[3];
      int np=acci[0];
      float npf=(float)np;
      float den2=fmaxf(2.f*npf,1.f);
      float lbox=accf[0]/den2+accf[1]/den2;
      float lcls=accf[2]/fmaxf(npf,1.f);
      float selc=npf+negcnt;
      float lobj=(accf[3]+negsum)/fmaxf(selc,1.f);
      out[0]=lbox+lcls+lobj;
      out[1]=lbox;
      out[2]=lobj;
      out[3]=lcls;
    }
  }
}

extern "C" void kernel_launch(void* const* d_in, const int* in_sizes, int n_in,
                              void* d_out, int out_size, void* d_ws, size_t ws_size,
                              hipStream_t stream) {
  const float* f0=(const float*)d_in[0];
  const float* f1=(const float*)d_in[1];
  const float* f2=(const float*)d_in[2];
  const float* tg=(const float*)d_in[3];
  const float* priors=(const float*)d_in[4];
  int nt = in_sizes[3]/6;
  if(nt>NT_MAX) nt=NT_MAX;
  if(nt<1) nt=1;

  char* ws=(char*)d_ws;
  int* bars=(int*)(ws+O_BAR);

  k_init0<<<1,64,0,stream>>>(bars);
  k_mega<<<NBLK,256,0,stream>>>(f0,f1,f2,tg,priors,nt,ws,(float*)d_out);
}

// Round 11
// 247.249 us; speedup vs baseline: 2.0207x; 2.0207x over previous
//
#include <hip/hip_runtime.h>
#include <math.h>

#define MTOT 42000
#define NB 8
#define NCLS 80
#define CAP_LIST 4096
#define MAXT 256
#define NT_MAX 2048
#define GX_MAIN 165                 // ceil(42000/256)
#define NBLK_MAIN (GX_MAIN*NB)      // 1320
#define NCH 32                      // bestprior chunks per target
#define CS 1313                     // ceil(42000/32)

// ---- workspace byte offsets ----
#define O_OVR 0
#define O_GIX (O_OVR + NB*MTOT*4)
#define O_OBJ (O_GIX + NB*MTOT*4)        // compact obj channel [NB][MTOT]
#define O_LSC (O_OBJ + NB*MTOT*4)
#define O_BCE (O_LSC + NB*MTOT*4)
#define O_LST (O_BCE + NB*MTOT*4)
#define O_LJ  (O_LST + NB*MAXT*4)
#define O_CNT (O_LJ + NT_MAX*4)
#define O_BPP (((O_CNT + 64 + 7)/8)*8)   // u64 partials [NT_MAX][NCH]
#define O_PA  (O_BPP + NT_MAX*NCH*8)     // posloss float4 partials [NBLK_MAIN]
#define O_PN  (O_PA + NBLK_MAIN*16)      // k_lc int partials [NBLK_MAIN]
#define O_P2  (O_PN + NBLK_MAIN*4)       // k_select float2 partials [NBLK_MAIN]
#define O_BINL (O_P2 + NBLK_MAIN*8)      // tie list [NB][CAP_LIST][2]
// kernel-zeroed region:
#define O_HA  (((O_BINL + NB*CAP_LIST*2*4 + 255)/256)*256)
#define O_HB  (O_HA + NB*256*4)
#define O_ACCI (O_HB + NB*256*4)
#define O_ZEND (O_ACCI + 128)
#define ZWORDS ((O_ZEND - O_HA)/4)
#define ZBLK ((ZWORDS + 255)/256)
// acci: [0]=num_pos [2..9]=coarse ca (then k_select/tf recompute fine locally)
//       [10..17]=kres [18..25]=tie list counters

__device__ __forceinline__ float iou_cxcywh(float acx,float acy,float aw,float ah,
                                            float bcx,float bcy,float bw,float bh){
  float ax0=acx-aw*0.5f, ay0=acy-ah*0.5f, ax1=acx+aw*0.5f, ay1=acy+ah*0.5f;
  float bx0=bcx-bw*0.5f, by0=bcy-bh*0.5f, bx1=bcx+bw*0.5f, by1=bcy+bh*0.5f;
  float tlx=fmaxf(ax0,bx0), tly=fmaxf(ay0,by0);
  float brx=fminf(ax1,bx1), bry=fminf(ay1,by1);
  float wx=fmaxf(brx-tlx,0.f), wy=fmaxf(bry-tly,0.f);
  float inter=wx*wy;
  return inter/(aw*ah+bw*bh-inter+1e-9f);
}

__device__ __forceinline__ float sl1(float x){
  float ax=fabsf(x); return ax<1.f ? 0.5f*ax*ax : ax-0.5f;
}

__device__ __forceinline__ void feat_base(const float* f0,const float* f1,const float* f2,
                                          int i,int m,const float** basep,int* hwp){
  const float* fp; int hw, loc;
  if(m<32000){ fp=f0; hw=6400; loc=m; }
  else if(m<40000){ fp=f1; hw=1600; loc=m-32000; }
  else { fp=f2; hw=400; loc=m-40000; }
  int a=loc/hw, p=loc-a*hw;
  *basep = fp + (size_t)(i*425 + a*85)*(size_t)hw + p;
  *hwp = hw;
}

// inline fine-scan: 16-bit boundary bin + residual
__device__ __forceinline__ void fine_scan(const unsigned* hb,int ca,int kres,int* bs_out,int* r_out){
  if(ca==0x7fffffff){ *bs_out=0x7fffffff; *r_out=0; return; }
  int run=0, bs=-1, r=0;
  for(int f=255;f>=0;f--){
    int cb=(int)hb[f];
    if(run<kres && run+cb>=kres){ bs=(ca<<8)|f; r=kres-run; break; }
    run+=cb;
  }
  if(bs<0){ bs=(ca<<8); r=kres-run; }
  *bs_out=bs; *r_out=r;
}

// fused: zero hist/acc region + per-image target prep (R8-proven pattern)
__global__ void k_init(const float* __restrict__ tg, int nt, int* __restrict__ list,
                       int* __restrict__ cnt, int* __restrict__ lj,
                       unsigned* __restrict__ zbase){
  int bx=blockIdx.x, tid=threadIdx.x;
  if(bx<ZBLK){
    int w=bx*256+tid;
    if(w<ZWORDS) zbase[w]=0u;
    return;
  }
  if(bx==ZBLK && tid<NB){
    int c=0;
    for(int q=0;q<nt;q++) if((int)tg[q*6]==tid) c++;
    cnt[tid]=c;
  }
  int t=(bx-ZBLK)*256+tid;
  if(t>=nt) return;
  int img=(int)tg[t*6];
  int j=0;
  for(int q=0;q<t;q++) if((int)tg[q*6]==img) j++;
  lj[t]=j;
  if(img>=0 && img<NB && j<MAXT) list[img*MAXT+j]=t;
}

// horizontal fusion: [0,1320) match | [1320,2640) obj prefetch | [2640,2640+nt*32) bpA
__global__ void k_big1(const float* __restrict__ f0,const float* __restrict__ f1,const float* __restrict__ f2,
                       const float* __restrict__ tg,const float* __restrict__ priors,
                       const int* __restrict__ list,const int* __restrict__ cnt,int nt,
                       float* __restrict__ ovr,int* __restrict__ gix,
                       float* __restrict__ objc,unsigned long long* __restrict__ bpp){
  __shared__ float st[MAXT*6];
  __shared__ int sidx[MAXT];
  __shared__ unsigned long long su[256];
  int b=blockIdx.x, tid=threadIdx.x;
  if(b<NBLK_MAIN){
    // ---- match ----
    int i=b/GX_MAIN, cb=b-(b/GX_MAIN)*GX_MAIN;
    int n=min(cnt[i],MAXT);
    for(int j=tid;j<n;j+=256){
      int t=list[i*MAXT+j];
      sidx[j]=t;
      #pragma unroll
      for(int q=0;q<6;q++) st[j*6+q]=tg[t*6+q];
    }
    __syncthreads();
    int m=cb*256+tid;
    if(m>=MTOT) return;
    float4 pr=((const float4*)priors)[m];
    float maxv=-1.f; int bi=0;
    for(int j=0;j<n;j++){
      float v=iou_cxcywh(st[j*6+2],st[j*6+3],st[j*6+4],st[j*6+5],pr.x,pr.y,pr.z,pr.w);
      if(v>maxv){ maxv=v; bi=sidx[j]; }
    }
    ovr[i*MTOT+m]=maxv; gix[i*MTOT+m]=bi;
  } else if(b<2*NBLK_MAIN){
    // ---- obj channel prefetch into compact array ----
    int idx=b-NBLK_MAIN;
    int i=idx/GX_MAIN, cb=idx-(idx/GX_MAIN)*GX_MAIN;
    int m=cb*256+tid;
    if(m>=MTOT) return;
    const float* base; int hw;
    feat_base(f0,f1,f2,i,m,&base,&hw);
    objc[i*MTOT+m]=base[(size_t)4*hw];
  } else {
    // ---- bpA: chunked best-prior partials ----
    int idx=b-2*NBLK_MAIN;
    int t=idx/NCH, c=idx-(idx/NCH)*NCH;
    float acx=tg[t*6+2],acy=tg[t*6+3],aw=tg[t*6+4],ah=tg[t*6+5];
    int m0=c*CS, m1=min(m0+CS,MTOT);
    float bv=-1.f; int bm=0;
    for(int m=m0+tid;m<m1;m+=256){
      float4 pr=((const float4*)priors)[m];
      float v=iou_cxcywh(acx,acy,aw,ah,pr.x,pr.y,pr.z,pr.w);
      if(v>bv){ bv=v; bm=m; }
    }
    unsigned long long p=(bv<0.f)?0ull
        :(((unsigned long long)__float_as_uint(bv))<<32)|(unsigned)(~bm);
    su[tid]=p;
    __syncthreads();
    for(int o=128;o>0;o>>=1){
      if(tid<o){ if(su[tid+o]>su[tid]) su[tid]=su[tid+o]; }
      __syncthreads();
    }
    if(tid==0) bpp[(size_t)t*NCH+c]=su[0];
  }
}

// bpB + forced-prior scatter, single block (tiny)
__global__ void k_bpsc(const float* __restrict__ tg,int nt,
                       const unsigned long long* __restrict__ bpp,
                       const int* __restrict__ lj,float* __restrict__ ovr){
  __shared__ int tbp[NT_MAX];
  __shared__ int timg[NT_MAX];
  int tid=threadIdx.x;
  for(int t=tid;t<nt;t+=256){
    unsigned long long best=0ull;
    const unsigned long long* pp=&bpp[(size_t)t*NCH];
    for(int c=0;c<NCH;c++){ unsigned long long v=pp[c]; if(v>best) best=v; }
    int bm=~((unsigned)(best&0xFFFFFFFFull));
    tbp[t]=min(max(bm,0),MTOT-1);
    timg[t]=(int)tg[t*6];
  }
  __syncthreads();
  for(int t=tid;t<nt;t+=256){
    int img=timg[t];
    if(img<0||img>=NB) continue;
    int myp=tbp[t];
    bool last=true;
    for(int q=t+1;q<nt;q++) if(timg[q]==img&&tbp[q]==myp){ last=false; break; }
    if(last) ovr[img*MTOT+myp]=(float)lj[t];
  }
}

// lc/bce from compact obj (contiguous), coarse hist, npos partials
__global__ void k_lc(const float* __restrict__ tg,const float* __restrict__ objc,
                     const float* __restrict__ ovr,const int* __restrict__ gix,int nt,
                     float* __restrict__ lsc,float* __restrict__ bcearr,
                     unsigned* __restrict__ histA,int* __restrict__ partN){
  __shared__ unsigned h[256];
  __shared__ int snp[4];
  int tid=threadIdx.x, lane=tid&63, wid=tid>>6;
  h[tid]=0u;
  __syncthreads();
  int i=blockIdx.y;
  int m=blockIdx.x*256+tid;
  int npos=0;
  if(m<MTOT){
    int gid=i*MTOT+m;
    float ov=ovr[gid];
    int gi=min(max(gix[gid],0),nt-1);
    float tc=tg[gi*6+1]+1.f;
    bool pos=(ov>=0.5f)&&(tc>0.f);
    float obj=objc[gid];
    float sp=log1pf(expf(-fabsf(obj)));
    float bce=fmaxf(obj,0.f)-(pos?obj:0.f)+sp;
    float lc=pos?0.f:(fmaxf(-obj,0.f)+sp);
    lsc[gid]=lc; bcearr[gid]=bce;
    atomicAdd(&h[__float_as_uint(lc)>>24],1u);
    npos=pos?1:0;
  }
  #pragma unroll
  for(int o=32;o>0;o>>=1) npos+=__shfl_xor(npos,o);
  if(lane==0) snp[wid]=npos;
  __syncthreads();
  unsigned hc=h[tid];
  if(hc) atomicAdd(&histA[i*256+tid],hc);
  if(tid==0) partN[blockIdx.y*GX_MAIN+blockIdx.x]=snp[0]+snp[1]+snp[2]+snp[3];
}

// np reduce + coarse scan (8 blocks)
__global__ void k_redscanA(const int* __restrict__ partN,const unsigned* __restrict__ histA,
                           int* __restrict__ acci){
  __shared__ int an[256];
  __shared__ unsigned h[256];
  int t=threadIdx.x, b=blockIdx.x;
  int n=0;
  for(int e=t;e<NBLK_MAIN;e+=256) n+=partN[e];
  an[t]=n;
  __syncthreads();
  for(int o=128;o>0;o>>=1){ if(t<o) an[t]+=an[t+o]; __syncthreads(); }
  int np=an[0];
  if(b==0&&t==0) acci[0]=np;
  h[t]=histA[b*256+t];
  __syncthreads();
  if(t==0){
    int kk=min(np,MTOT-np);
    if(kk<=0){ acci[2+b]=0x7fffffff; acci[10+b]=0; }
    else{
      int run=0, ca=-1, kres=0;
      for(int c2=255;c2>=0;c2--){
        int cbn=(int)h[c2];
        if(run<kk&&run+cbn>=kk){ ca=c2; kres=kk-run; break; }
        run+=cbn;
      }
      if(ca<0){ ca=0; kres=kk-run; }
      acci[2+b]=ca; acci[10+b]=kres;
    }
  }
}

// horizontal fusion: [0,1320) fine hist | [1320,2640) positive box+CE losses
__global__ void k_big2(const float* __restrict__ f0,const float* __restrict__ f1,const float* __restrict__ f2,
                       const float* __restrict__ tg,const float* __restrict__ priors,
                       const float* __restrict__ ovr,const int* __restrict__ gix,
                       const float* __restrict__ lsc,const float* __restrict__ bcearr,
                       const int* __restrict__ acci,int nt,
                       unsigned* __restrict__ histB,float4* __restrict__ partA){
  __shared__ unsigned h[256];
  __shared__ float rA[4],rB[4],rC[4],rD[4];
  int b=blockIdx.x, tid=threadIdx.x, lane=tid&63, wid=tid>>6;
  if(b<NBLK_MAIN){
    // ---- fine hist ----
    h[tid]=0u;
    __syncthreads();
    int i=b/GX_MAIN, cb=b-(b/GX_MAIN)*GX_MAIN;
    int ca=acci[2+i];
    int m=cb*256+tid;
    if(m<MTOT && ca!=0x7fffffff){
      unsigned u=__float_as_uint(lsc[i*MTOT+m]);
      if((int)(u>>24)==ca) atomicAdd(&h[(u>>16)&0xFF],1u);
    }
    __syncthreads();
    unsigned c=h[tid];
    if(c) atomicAdd(&histB[i*256+tid],c);
  } else {
    // ---- positive losses: box + bce_pos + wave-cooperative CE ----
    int idx=b-NBLK_MAIN;
    int i=idx/GX_MAIN, cb=idx-(idx/GX_MAIN)*GX_MAIN;
    int m=cb*256+tid;
    bool valid=(m<MTOT);
    float lxy=0.f,lwh=0.f,bcep=0.f,wce=0.f;
    bool pos=false; int gi=0;
    if(valid){
      int gid=i*MTOT+m;
      float ov=ovr[gid];
      gi=min(max(gix[gid],0),nt-1);
      float tc=tg[gi*6+1]+1.f;
      pos=(ov>=0.5f)&&(tc>0.f);
      if(pos){
        const float* base; int hw;
        feat_base(f0,f1,f2,i,m,&base,&hw);
        bcep=bcearr[gid];
        float4 pr=((const float4*)priors)[m];
        float bx=tg[gi*6+2],by=tg[gi*6+3],bw=tg[gi*6+4],bh=tg[gi*6+5];
        float tx=(bx-pr.x)/pr.z, ty=(by-pr.y)/pr.w;
        float tw=logf(bw/pr.z), th=logf(bh/pr.w);
        lxy=sl1(base[0]-tx)+sl1(base[(size_t)hw]-ty);
        lwh=sl1(base[(size_t)2*hw]-tw)+sl1(base[(size_t)3*hw]-th);
      }
    }
    // wave-cooperative CE
    unsigned long long mask=__ballot(valid&&pos);
    while(mask){
      int s=__ffsll(mask)-1;
      mask&=mask-1;
      int m_s=__shfl(m,s);
      int gi_s=__shfl(gi,s);
      const float* bs2; int hws;
      feat_base(f0,f1,f2,i,m_s,&bs2,&hws);
      int label=(int)(tg[gi_s*6+1]+1.f)-1;
      label=min(NCLS-1,max(0,label));
      float v0=bs2[(size_t)(5+lane)*hws];
      float v1=(lane<16)?bs2[(size_t)(69+lane)*hws]:-3.0e38f;
      float mx=fmaxf(v0,v1);
      #pragma unroll
      for(int o=32;o>0;o>>=1) mx=fmaxf(mx,__shfl_xor(mx,o));
      float se=expf(v0-mx)+((lane<16)?expf(v1-mx):0.f);
      float xl=((lane==label)?v0:0.f)+((lane<16&&lane+64==label)?v1:0.f);
      #pragma unroll
      for(int o=32;o>0;o>>=1){ se+=__shfl_xor(se,o); xl+=__shfl_xor(xl,o); }
      wce+=logf(se)+mx-xl;   // identical on all lanes; add once per wave below
    }
    #pragma unroll
    for(int o=32;o>0;o>>=1){
      lxy+=__shfl_xor(lxy,o); lwh+=__shfl_xor(lwh,o); bcep+=__shfl_xor(bcep,o);
    }
    if(lane==0){ rA[wid]=lxy; rB[wid]=lwh; rC[wid]=wce; rD[wid]=bcep; }
    __syncthreads();
    if(tid==0)
      partA[idx]=make_float4(rA[0]+rA[1]+rA[2]+rA[3], rB[0]+rB[1]+rB[2]+rB[3],
                             rC[0]+rC[1]+rC[2]+rC[3], rD[0]+rD[1]+rD[2]+rD[3]);
  }
}

// select negatives above 16-bit threshold (fine_scan locally); partials + tie list
__global__ void k_select(const float* __restrict__ lsc,const float* __restrict__ bcearr,
                         const unsigned* __restrict__ histB,
                         int* __restrict__ acci,float2* __restrict__ part2,
                         int* __restrict__ binlist){
  __shared__ unsigned hb[256];
  __shared__ int sbs;
  __shared__ float ss[4]; __shared__ float sc[4];
  int tid=threadIdx.x, lane=tid&63, wid=tid>>6;
  int i=blockIdx.y;
  int ca=acci[2+i], kres=acci[10+i];
  hb[tid]=(ca==0x7fffffff)?0u:histB[i*256+tid];
  __syncthreads();
  if(tid==0){ int bs,r; fine_scan(hb,ca,kres,&bs,&r); sbs=bs; }
  __syncthreads();
  int bs_=sbs;
  int m=blockIdx.x*256+tid;
  float s=0.f, c=0.f;
  if(m<MTOT){
    int gid=i*MTOT+m;
    unsigned u=__float_as_uint(lsc[gid]);
    int bin=(int)(u>>16);
    if(bin>bs_){ s=bcearr[gid]; c=1.f; }
    else if(bin==bs_){
      int idx=atomicAdd(&acci[18+i],1);
      if(idx<CAP_LIST){
        binlist[((size_t)i*CAP_LIST+idx)*2  ]=(int)u;
        binlist[((size_t)i*CAP_LIST+idx)*2+1]=gid;
      }
    }
  }
  #pragma unroll
  for(int o=32;o>0;o>>=1){ s+=__shfl_xor(s,o); c+=__shfl_xor(c,o); }
  if(lane==0){ ss[wid]=s; sc[wid]=c; }
  __syncthreads();
  if(tid==0) part2[blockIdx.y*gridDim.x+blockIdx.x]=make_float2(ss[0]+ss[1]+ss[2]+ss[3], sc[0]+sc[1]+sc[2]+sc[3]);
}

// fused: reduce partA/part2 + tie resolution + final combine (1 block)
__global__ void k_tf(const float4* __restrict__ partA,const float2* __restrict__ part2,
                     const float* __restrict__ bcearr,const unsigned* __restrict__ histB,
                     const int* __restrict__ acci,const int* __restrict__ binlist,
                     float* __restrict__ out){
  __shared__ float a0[256],a1[256],a2[256],a3[256],s0[256],s1[256];
  __shared__ unsigned hb[256];
  __shared__ int sbs, sr;
  int tid=threadIdx.x, lane=tid&63, wid=tid>>6;
  float x=0,y=0,z=0,w=0,ns=0,nc=0;
  for(int e=tid;e<NBLK_MAIN;e+=256){
    float4 p=partA[e]; x+=p.x; y+=p.y; z+=p.z; w+=p.w;
    float2 q=part2[e]; ns+=q.x; nc+=q.y;
  }
  a0[tid]=x; a1[tid]=y; a2[tid]=z; a3[tid]=w; s0[tid]=ns; s1[tid]=nc;
  __syncthreads();
  for(int o=128;o>0;o>>=1){
    if(tid<o){
      a0[tid]+=a0[tid+o]; a1[tid]+=a1[tid+o]; a2[tid]+=a2[tid+o]; a3[tid]+=a3[tid+o];
      s0[tid]+=s0[tid+o]; s1[tid]+=s1[tid+o];
    }
    __syncthreads();
  }
  float sum_xy=a0[0], sum_wh=a1[0], sum_ce=a2[0], sum_bcep=a3[0];
  float negsum=s0[0], negcnt=s1[0];
  // tie resolution per image
  float tsum=0.f; int tcnt=0;
  for(int i=0;i<NB;i++){
    int ca=acci[2+i], kres=acci[10+i];
    __syncthreads();
    hb[tid]=(ca==0x7fffffff)?0u:histB[i*256+tid];
    __syncthreads();
    if(tid==0){ int bs,r; fine_scan(hb,ca,kres,&bs,&r); sbs=bs; sr=r; }
    __syncthreads();
    if(sbs==0x7fffffff) continue;
    int n=min(acci[18+i],CAP_LIST);
    int r=sr;
    for(int e=tid;e<n;e+=256){
      unsigned ue=(unsigned)binlist[((size_t)i*CAP_LIST+e)*2];
      int ge=binlist[((size_t)i*CAP_LIST+e)*2+1];
      int rank=0;
      for(int q=0;q<n;q++){
        unsigned uq=(unsigned)binlist[((size_t)i*CAP_LIST+q)*2];
        int gq=binlist[((size_t)i*CAP_LIST+q)*2+1];
        rank += ((uq>ue)||(uq==ue&&gq<ge))?1:0;
      }
      if(rank<r){ tsum+=bcearr[ge]; tcnt++; }
    }
  }
  float ftc=(float)tcnt;
  #pragma unroll
  for(int o=32;o>0;o>>=1){ tsum+=__shfl_xor(tsum,o); ftc+=__shfl_xor(ftc,o); }
  __syncthreads();
  if(lane==0){ a0[wid]=tsum; a1[wid]=ftc; }
  __syncthreads();
  if(tid==0){
    negsum+=a0[0]+a0[1]+a0[2]+a0[3];
    negcnt+=a1[0]+a1[1]+a1[2]+a1[3];
    int np=acci[0];
    float npf=(float)np;
    float den2=fmaxf(2.f*npf,1.f);
    float lbox=sum_xy/den2+sum_wh/den2;
    float lcls=sum_ce/fmaxf(npf,1.f);
    float selc=npf+negcnt;
    float lobj=(sum_bcep+negsum)/fmaxf(selc,1.f);
    out[0]=lbox+lcls+lobj;
    out[1]=lbox;
    out[2]=lobj;
    out[3]=lcls;
  }
}

extern "C" void kernel_launch(void* const* d_in, const int* in_sizes, int n_in,
                              void* d_out, int out_size, void* d_ws, size_t ws_size,
                              hipStream_t stream) {
  const float* f0=(const float*)d_in[0];
  const float* f1=(const float*)d_in[1];
  const float* f2=(const float*)d_in[2];
  const float* tg=(const float*)d_in[3];
  const float* priors=(const float*)d_in[4];
  int nt = in_sizes[3]/6;
  if(nt>NT_MAX) nt=NT_MAX;
  if(nt<1) nt=1;

  char* ws=(char*)d_ws;
  float*    ovr    =(float*)   (ws+O_OVR);
  int*      gix    =(int*)     (ws+O_GIX);
  float*    objc   =(float*)   (ws+O_OBJ);
  float*    lsc    =(float*)   (ws+O_LSC);
  float*    bcearr =(float*)   (ws+O_BCE);
  int*      list   =(int*)     (ws+O_LST);
  int*      lj     =(int*)     (ws+O_LJ);
  int*      cnt    =(int*)     (ws+O_CNT);
  unsigned long long* bpp=(unsigned long long*)(ws+O_BPP);
  float4*   partA  =(float4*)  (ws+O_PA);
  int*      partN  =(int*)     (ws+O_PN);
  float2*   part2  =(float2*)  (ws+O_P2);
  int*      binlist=(int*)     (ws+O_BINL);
  unsigned* histA  =(unsigned*)(ws+O_HA);
  unsigned* histB  =(unsigned*)(ws+O_HB);
  int*      acci   =(int*)     (ws+O_ACCI);
  unsigned* zbase  =(unsigned*)(ws+O_HA);

  int ntb=(nt+255)/256;
  k_init<<<ZBLK+ntb,256,0,stream>>>(tg,nt,list,cnt,lj,zbase);
  k_big1<<<2*NBLK_MAIN+nt*NCH,256,0,stream>>>(f0,f1,f2,tg,priors,list,cnt,nt,ovr,gix,objc,bpp);
  k_bpsc<<<1,256,0,stream>>>(tg,nt,bpp,lj,ovr);
  dim3 gm(GX_MAIN, NB);
  k_lc<<<gm,256,0,stream>>>(tg,objc,ovr,gix,nt,lsc,bcearr,histA,partN);
  k_redscanA<<<NB,256,0,stream>>>(partN,histA,acci);
  k_big2<<<2*NBLK_MAIN,256,0,stream>>>(f0,f1,f2,tg,priors,ovr,gix,lsc,bcearr,acci,nt,histB,partA);
  k_select<<<gm,256,0,stream>>>(lsc,bcearr,histB,acci,part2,binlist);
  k_tf<<<1,256,0,stream>>>(partA,part2,bcearr,histB,acci,binlist,(float*)d_out);
}

// Round 12
// 138.333 us; speedup vs baseline: 3.6118x; 1.7874x over previous
//
#include <hip/hip_runtime.h>
#include <math.h>

#define MTOT 42000
#define NB 8
#define NCLS 80
#define CAP_LIST 4096
#define MAXT 256
#define NT_MAX 2048
#define GX_MAIN 165                 // ceil(42000/256)
#define NBLK_MAIN (GX_MAIN*NB)      // 1320
#define NCH 32                      // bestprior chunks per target
#define CS 1313                     // ceil(42000/32)

// ---- workspace byte offsets ----
#define O_OVR 0
#define O_GIX (O_OVR + NB*MTOT*4)
#define O_OBJ (O_GIX + NB*MTOT*4)        // compact obj channel [NB][MTOT]
#define O_LSC (O_OBJ + NB*MTOT*4)
#define O_BCE (O_LSC + NB*MTOT*4)
#define O_LST (O_BCE + NB*MTOT*4)
#define O_LJ  (O_LST + NB*MAXT*4)
#define O_CNT (O_LJ + NT_MAX*4)
#define O_BPP (((O_CNT + 64 + 7)/8)*8)   // u64 partials [NT_MAX][NCH]
#define O_PA  (O_BPP + NT_MAX*NCH*8)     // posloss float4 partials [NBLK_MAIN]
#define O_PN  (O_PA + NBLK_MAIN*16)      // k_lc int partials [NBLK_MAIN]
#define O_P2  (O_PN + NBLK_MAIN*4)       // k_select float2 partials [NBLK_MAIN]
#define O_BINL (O_P2 + NBLK_MAIN*8)      // tie list [NB][CAP_LIST][2]
// kernel-zeroed region:
#define O_HA  (((O_BINL + NB*CAP_LIST*2*4 + 255)/256)*256)
#define O_HB  (O_HA + NB*256*4)
#define O_ACC (O_HB + NB*256*4)          // accf[0..15]: [5]=tie bce sum
#define O_ACCI (O_ACC + 64)              // acci[0..31]
#define O_ZEND (O_ACCI + 128)
#define ZWORDS ((O_ZEND - O_HA)/4)
#define ZBLK ((ZWORDS + 255)/256)
// acci: [0]=num_pos [1]=tie negsel cnt [2..9]=coarse ca [10..17]=kres [18..25]=tie listn

__device__ __forceinline__ float iou_cxcywh(float acx,float acy,float aw,float ah,
                                            float bcx,float bcy,float bw,float bh){
  float ax0=acx-aw*0.5f, ay0=acy-ah*0.5f, ax1=acx+aw*0.5f, ay1=acy+ah*0.5f;
  float bx0=bcx-bw*0.5f, by0=bcy-bh*0.5f, bx1=bcx+bw*0.5f, by1=bcy+bh*0.5f;
  float tlx=fmaxf(ax0,bx0), tly=fmaxf(ay0,by0);
  float brx=fminf(ax1,bx1), bry=fminf(ay1,by1);
  float wx=fmaxf(brx-tlx,0.f), wy=fmaxf(bry-tly,0.f);
  float inter=wx*wy;
  return inter/(aw*ah+bw*bh-inter+1e-9f);
}

__device__ __forceinline__ float sl1(float x){
  float ax=fabsf(x); return ax<1.f ? 0.5f*ax*ax : ax-0.5f;
}

__device__ __forceinline__ void feat_base(const float* f0,const float* f1,const float* f2,
                                          int i,int m,const float** basep,int* hwp){
  const float* fp; int hw, loc;
  if(m<32000){ fp=f0; hw=6400; loc=m; }
  else if(m<40000){ fp=f1; hw=1600; loc=m-32000; }
  else { fp=f2; hw=400; loc=m-40000; }
  int a=loc/hw, p=loc-a*hw;
  *basep = fp + (size_t)(i*425 + a*85)*(size_t)hw + p;
  *hwp = hw;
}

// inline fine-scan: 16-bit boundary bin + residual
__device__ __forceinline__ void fine_scan(const unsigned* hb,int ca,int kres,int* bs_out,int* r_out){
  if(ca==0x7fffffff){ *bs_out=0x7fffffff; *r_out=0; return; }
  int run=0, bs=-1, r=0;
  for(int f=255;f>=0;f--){
    int cb=(int)hb[f];
    if(run<kres && run+cb>=kres){ bs=(ca<<8)|f; r=kres-run; break; }
    run+=cb;
  }
  if(bs<0){ bs=(ca<<8); r=kres-run; }
  *bs_out=bs; *r_out=r;
}

// fused: zero hist/acc region + per-image target prep
__global__ void k_init(const float* __restrict__ tg, int nt, int* __restrict__ list,
                       int* __restrict__ cnt, int* __restrict__ lj,
                       unsigned* __restrict__ zbase){
  int bx=blockIdx.x, tid=threadIdx.x;
  if(bx<ZBLK){
    int w=bx*256+tid;
    if(w<ZWORDS) zbase[w]=0u;
    return;
  }
  if(bx==ZBLK && tid<NB){
    int c=0;
    for(int q=0;q<nt;q++) if((int)tg[q*6]==tid) c++;
    cnt[tid]=c;
  }
  int t=(bx-ZBLK)*256+tid;
  if(t>=nt) return;
  int img=(int)tg[t*6];
  int j=0;
  for(int q=0;q<t;q++) if((int)tg[q*6]==img) j++;
  lj[t]=j;
  if(img>=0 && img<NB && j<MAXT) list[img*MAXT+j]=t;
}

// horizontal fusion: [0,1320) match | [1320,2640) obj prefetch | [2640,2640+nt*32) bpA
__global__ void k_big1(const float* __restrict__ f0,const float* __restrict__ f1,const float* __restrict__ f2,
                       const float* __restrict__ tg,const float* __restrict__ priors,
                       const int* __restrict__ list,const int* __restrict__ cnt,int nt,
                       float* __restrict__ ovr,int* __restrict__ gix,
                       float* __restrict__ objc,unsigned long long* __restrict__ bpp){
  __shared__ float st[MAXT*6];
  __shared__ int sidx[MAXT];
  __shared__ unsigned long long su[256];
  int b=blockIdx.x, tid=threadIdx.x;
  if(b<NBLK_MAIN){
    int i=b/GX_MAIN, cb=b-(b/GX_MAIN)*GX_MAIN;
    int n=min(cnt[i],MAXT);
    for(int j=tid;j<n;j+=256){
      int t=list[i*MAXT+j];
      sidx[j]=t;
      #pragma unroll
      for(int q=0;q<6;q++) st[j*6+q]=tg[t*6+q];
    }
    __syncthreads();
    int m=cb*256+tid;
    if(m>=MTOT) return;
    float4 pr=((const float4*)priors)[m];
    float maxv=-1.f; int bi=0;
    for(int j=0;j<n;j++){
      float v=iou_cxcywh(st[j*6+2],st[j*6+3],st[j*6+4],st[j*6+5],pr.x,pr.y,pr.z,pr.w);
      if(v>maxv){ maxv=v; bi=sidx[j]; }
    }
    ovr[i*MTOT+m]=maxv; gix[i*MTOT+m]=bi;
  } else if(b<2*NBLK_MAIN){
    int idx=b-NBLK_MAIN;
    int i=idx/GX_MAIN, cb=idx-(idx/GX_MAIN)*GX_MAIN;
    int m=cb*256+tid;
    if(m>=MTOT) return;
    const float* base; int hw;
    feat_base(f0,f1,f2,i,m,&base,&hw);
    objc[i*MTOT+m]=base[(size_t)4*hw];
  } else {
    int idx=b-2*NBLK_MAIN;
    int t=idx/NCH, c=idx-(idx/NCH)*NCH;
    float acx=tg[t*6+2],acy=tg[t*6+3],aw=tg[t*6+4],ah=tg[t*6+5];
    int m0=c*CS, m1=min(m0+CS,MTOT);
    float bv=-1.f; int bm=0;
    for(int m=m0+tid;m<m1;m+=256){
      float4 pr=((const float4*)priors)[m];
      float v=iou_cxcywh(acx,acy,aw,ah,pr.x,pr.y,pr.z,pr.w);
      if(v>bv){ bv=v; bm=m; }
    }
    unsigned long long p=(bv<0.f)?0ull
        :(((unsigned long long)__float_as_uint(bv))<<32)|(unsigned)(~bm);
    su[tid]=p;
    __syncthreads();
    for(int o=128;o>0;o>>=1){
      if(tid<o){ if(su[tid+o]>su[tid]) su[tid]=su[tid+o]; }
      __syncthreads();
    }
    if(tid==0) bpp[(size_t)t*NCH+c]=su[0];
  }
}

// bpB + forced-prior scatter, single block (tiny)
__global__ void k_bpsc(const float* __restrict__ tg,int nt,
                       const unsigned long long* __restrict__ bpp,
                       const int* __restrict__ lj,float* __restrict__ ovr){
  __shared__ int tbp[NT_MAX];
  __shared__ int timg[NT_MAX];
  int tid=threadIdx.x;
  for(int t=tid;t<nt;t+=256){
    unsigned long long best=0ull;
    const unsigned long long* pp=&bpp[(size_t)t*NCH];
    for(int c=0;c<NCH;c++){ unsigned long long v=pp[c]; if(v>best) best=v; }
    int bm=~((unsigned)(best&0xFFFFFFFFull));
    tbp[t]=min(max(bm,0),MTOT-1);
    timg[t]=(int)tg[t*6];
  }
  __syncthreads();
  for(int t=tid;t<nt;t+=256){
    int img=timg[t];
    if(img<0||img>=NB) continue;
    int myp=tbp[t];
    bool last=true;
    for(int q=t+1;q<nt;q++) if(timg[q]==img&&tbp[q]==myp){ last=false; break; }
    if(last) ovr[img*MTOT+myp]=(float)lj[t];
  }
}

// lc/bce from compact obj (contiguous), coarse hist, npos partials
__global__ void k_lc(const float* __restrict__ tg,const float* __restrict__ objc,
                     const float* __restrict__ ovr,const int* __restrict__ gix,int nt,
                     float* __restrict__ lsc,float* __restrict__ bcearr,
                     unsigned* __restrict__ histA,int* __restrict__ partN){
  __shared__ unsigned h[256];
  __shared__ int snp[4];
  int tid=threadIdx.x, lane=tid&63, wid=tid>>6;
  h[tid]=0u;
  __syncthreads();
  int i=blockIdx.y;
  int m=blockIdx.x*256+tid;
  int npos=0;
  if(m<MTOT){
    int gid=i*MTOT+m;
    float ov=ovr[gid];
    int gi=min(max(gix[gid],0),nt-1);
    float tc=tg[gi*6+1]+1.f;
    bool pos=(ov>=0.5f)&&(tc>0.f);
    float obj=objc[gid];
    float sp=log1pf(expf(-fabsf(obj)));
    float bce=fmaxf(obj,0.f)-(pos?obj:0.f)+sp;
    float lc=pos?0.f:(fmaxf(-obj,0.f)+sp);
    lsc[gid]=lc; bcearr[gid]=bce;
    atomicAdd(&h[__float_as_uint(lc)>>24],1u);
    npos=pos?1:0;
  }
  #pragma unroll
  for(int o=32;o>0;o>>=1) npos+=__shfl_xor(npos,o);
  if(lane==0) snp[wid]=npos;
  __syncthreads();
  unsigned hc=h[tid];
  if(hc) atomicAdd(&histA[i*256+tid],hc);
  if(tid==0) partN[blockIdx.y*GX_MAIN+blockIdx.x]=snp[0]+snp[1]+snp[2]+snp[3];
}

// np reduce + coarse scan (8 blocks)
__global__ void k_redscanA(const int* __restrict__ partN,const unsigned* __restrict__ histA,
                           int* __restrict__ acci){
  __shared__ int an[256];
  __shared__ unsigned h[256];
  int t=threadIdx.x, b=blockIdx.x;
  int n=0;
  for(int e=t;e<NBLK_MAIN;e+=256) n+=partN[e];
  an[t]=n;
  __syncthreads();
  for(int o=128;o>0;o>>=1){ if(t<o) an[t]+=an[t+o]; __syncthreads(); }
  int np=an[0];
  if(b==0&&t==0) acci[0]=np;
  h[t]=histA[b*256+t];
  __syncthreads();
  if(t==0){
    int kk=min(np,MTOT-np);
    if(kk<=0){ acci[2+b]=0x7fffffff; acci[10+b]=0; }
    else{
      int run=0, ca=-1, kres=0;
      for(int c2=255;c2>=0;c2--){
        int cbn=(int)h[c2];
        if(run<kk&&run+cbn>=kk){ ca=c2; kres=kk-run; break; }
        run+=cbn;
      }
      if(ca<0){ ca=0; kres=kk-run; }
      acci[2+b]=ca; acci[10+b]=kres;
    }
  }
}

// horizontal fusion: [0,1320) fine hist | [1320,2640) positive box+CE losses
__global__ void k_big2(const float* __restrict__ f0,const float* __restrict__ f1,const float* __restrict__ f2,
                       const float* __restrict__ tg,const float* __restrict__ priors,
                       const float* __restrict__ ovr,const int* __restrict__ gix,
                       const float* __restrict__ lsc,const float* __restrict__ bcearr,
                       const int* __restrict__ acci,int nt,
                       unsigned* __restrict__ histB,float4* __restrict__ partA){
  __shared__ unsigned h[256];
  __shared__ float rA[4],rB[4],rC[4],rD[4];
  int b=blockIdx.x, tid=threadIdx.x, lane=tid&63, wid=tid>>6;
  if(b<NBLK_MAIN){
    h[tid]=0u;
    __syncthreads();
    int i=b/GX_MAIN, cb=b-(b/GX_MAIN)*GX_MAIN;
    int ca=acci[2+i];
    int m=cb*256+tid;
    if(m<MTOT && ca!=0x7fffffff){
      unsigned u=__float_as_uint(lsc[i*MTOT+m]);
      if((int)(u>>24)==ca) atomicAdd(&h[(u>>16)&0xFF],1u);
    }
    __syncthreads();
    unsigned c=h[tid];
    if(c) atomicAdd(&histB[i*256+tid],c);
  } else {
    int idx=b-NBLK_MAIN;
    int i=idx/GX_MAIN, cb=idx-(idx/GX_MAIN)*GX_MAIN;
    int m=cb*256+tid;
    bool valid=(m<MTOT);
    float lxy=0.f,lwh=0.f,bcep=0.f,wce=0.f;
    bool pos=false; int gi=0;
    if(valid){
      int gid=i*MTOT+m;
      float ov=ovr[gid];
      gi=min(max(gix[gid],0),nt-1);
      float tc=tg[gi*6+1]+1.f;
      pos=(ov>=0.5f)&&(tc>0.f);
      if(pos){
        const float* base; int hw;
        feat_base(f0,f1,f2,i,m,&base,&hw);
        bcep=bcearr[gid];
        float4 pr=((const float4*)priors)[m];
        float bx=tg[gi*6+2],by=tg[gi*6+3],bw=tg[gi*6+4],bh=tg[gi*6+5];
        float tx=(bx-pr.x)/pr.z, ty=(by-pr.y)/pr.w;
        float tw=logf(bw/pr.z), th=logf(bh/pr.w);
        lxy=sl1(base[0]-tx)+sl1(base[(size_t)hw]-ty);
        lwh=sl1(base[(size_t)2*hw]-tw)+sl1(base[(size_t)3*hw]-th);
      }
    }
    unsigned long long mask=__ballot(valid&&pos);
    while(mask){
      int s=__ffsll(mask)-1;
      mask&=mask-1;
      int m_s=__shfl(m,s);
      int gi_s=__shfl(gi,s);
      const float* bs2; int hws;
      feat_base(f0,f1,f2,i,m_s,&bs2,&hws);
      int label=(int)(tg[gi_s*6+1]+1.f)-1;
      label=min(NCLS-1,max(0,label));
      float v0=bs2[(size_t)(5+lane)*hws];
      float v1=(lane<16)?bs2[(size_t)(69+lane)*hws]:-3.0e38f;
      float mx=fmaxf(v0,v1);
      #pragma unroll
      for(int o=32;o>0;o>>=1) mx=fmaxf(mx,__shfl_xor(mx,o));
      float se=expf(v0-mx)+((lane<16)?expf(v1-mx):0.f);
      float xl=((lane==label)?v0:0.f)+((lane<16&&lane+64==label)?v1:0.f);
      #pragma unroll
      for(int o=32;o>0;o>>=1){ se+=__shfl_xor(se,o); xl+=__shfl_xor(xl,o); }
      wce+=logf(se)+mx-xl;
    }
    #pragma unroll
    for(int o=32;o>0;o>>=1){
      lxy+=__shfl_xor(lxy,o); lwh+=__shfl_xor(lwh,o); bcep+=__shfl_xor(bcep,o);
    }
    if(lane==0){ rA[wid]=lxy; rB[wid]=lwh; rC[wid]=wce; rD[wid]=bcep; }
    __syncthreads();
    if(tid==0)
      partA[idx]=make_float4(rA[0]+rA[1]+rA[2]+rA[3], rB[0]+rB[1]+rB[2]+rB[3],
                             rC[0]+rC[1]+rC[2]+rC[3], rD[0]+rD[1]+rD[2]+rD[3]);
  }
}

// select negatives above 16-bit threshold (fine_scan locally); partials + tie list
__global__ void k_select(const float* __restrict__ lsc,const float* __restrict__ bcearr,
                         const unsigned* __restrict__ histB,
                         int* __restrict__ acci,float2* __restrict__ part2,
                         int* __restrict__ binlist){
  __shared__ unsigned hb[256];
  __shared__ int sbs;
  __shared__ float ss[4]; __shared__ float sc[4];
  int tid=threadIdx.x, lane=tid&63, wid=tid>>6;
  int i=blockIdx.y;
  int ca=acci[2+i], kres=acci[10+i];
  hb[tid]=(ca==0x7fffffff)?0u:histB[i*256+tid];
  __syncthreads();
  if(tid==0){ int bs,r; fine_scan(hb,ca,kres,&bs,&r); sbs=bs; }
  __syncthreads();
  int bs_=sbs;
  int m=blockIdx.x*256+tid;
  float s=0.f, c=0.f;
  if(m<MTOT){
    int gid=i*MTOT+m;
    unsigned u=__float_as_uint(lsc[gid]);
    int bin=(int)(u>>16);
    if(bin>bs_){ s=bcearr[gid]; c=1.f; }
    else if(bin==bs_){
      int idx=atomicAdd(&acci[18+i],1);
      if(idx<CAP_LIST){
        binlist[((size_t)i*CAP_LIST+idx)*2  ]=(int)u;
        binlist[((size_t)i*CAP_LIST+idx)*2+1]=gid;
      }
    }
  }
  #pragma unroll
  for(int o=32;o>0;o>>=1){ s+=__shfl_xor(s,o); c+=__shfl_xor(c,o); }
  if(lane==0){ ss[wid]=s; sc[wid]=c; }
  __syncthreads();
  if(tid==0) part2[blockIdx.y*gridDim.x+blockIdx.x]=make_float2(ss[0]+ss[1]+ss[2]+ss[3], sc[0]+sc[1]+sc[2]+sc[3]);
}

// stable tie-resolution, one block per image (R8-proven); results into accf[5]/acci[1]
__global__ void k_ties(const float* __restrict__ bcearr,int* __restrict__ acci,
                       float* __restrict__ accf,const int* __restrict__ binlist,
                       const unsigned* __restrict__ histB){
  __shared__ unsigned hb[256];
  __shared__ int sbs, sr;
  int i=blockIdx.x, tid=threadIdx.x;
  int ca=acci[2+i], kres=acci[10+i];
  hb[tid]=(ca==0x7fffffff)?0u:histB[i*256+tid];
  __syncthreads();
  if(tid==0){ int bs,r; fine_scan(hb,ca,kres,&bs,&r); sbs=bs; sr=r; }
  __syncthreads();
  if(sbs==0x7fffffff) return;
  int n=min(acci[18+i],CAP_LIST);
  int r=sr;
  for(int e=tid;e<n;e+=blockDim.x){
    unsigned ue=(unsigned)binlist[((size_t)i*CAP_LIST+e)*2];
    int ge=binlist[((size_t)i*CAP_LIST+e)*2+1];
    int rank=0;
    for(int q=0;q<n;q++){
      unsigned uq=(unsigned)binlist[((size_t)i*CAP_LIST+q)*2];
      int gq=binlist[((size_t)i*CAP_LIST+q)*2+1];
      rank += ((uq>ue)||(uq==ue&&gq<ge))?1:0;
    }
    if(rank<r){
      atomicAdd(&accf[5], bcearr[ge]);
      atomicAdd(&acci[1], 1);
    }
  }
}

// final: reduce partA/part2 + combine (1 block)
__global__ void k_final(const float4* __restrict__ partA,const float2* __restrict__ part2,
                        const float* __restrict__ accf,const int* __restrict__ acci,
                        float* __restrict__ out){
  __shared__ float a0[256],a1[256],a2[256],a3[256],s0[256],s1[256];
  int tid=threadIdx.x;
  float x=0,y=0,z=0,w=0,ns=0,nc=0;
  for(int e=tid;e<NBLK_MAIN;e+=256){
    float4 p=partA[e]; x+=p.x; y+=p.y; z+=p.z; w+=p.w;
    float2 q=part2[e]; ns+=q.x; nc+=q.y;
  }
  a0[tid]=x; a1[tid]=y; a2[tid]=z; a3[tid]=w; s0[tid]=ns; s1[tid]=nc;
  __syncthreads();
  for(int o=128;o>0;o>>=1){
    if(tid<o){
      a0[tid]+=a0[tid+o]; a1[tid]+=a1[tid+o]; a2[tid]+=a2[tid+o]; a3[tid]+=a3[tid+o];
      s0[tid]+=s0[tid+o]; s1[tid]+=s1[tid+o];
    }
    __syncthreads();
  }
  if(tid==0){
    float negsum=s0[0]+accf[5];
    float negcnt=s1[0]+(float)acci[1];
    int np=acci[0];
    float npf=(float)np;
    float den2=fmaxf(2.f*npf,1.f);
    float lbox=a0[0]/den2+a1[0]/den2;
    float lcls=a2[0]/fmaxf(npf,1.f);
    float selc=npf+negcnt;
    float lobj=(a3[0]+negsum)/fmaxf(selc,1.f);
    out[0]=lbox+lcls+lobj;
    out[1]=lbox;
    out[2]=lobj;
    out[3]=lcls;
  }
}

extern "C" void kernel_launch(void* const* d_in, const int* in_sizes, int n_in,
                              void* d_out, int out_size, void* d_ws, size_t ws_size,
                              hipStream_t stream) {
  const float* f0=(const float*)d_in[0];
  const float* f1=(const float*)d_in[1];
  const float* f2=(const float*)d_in[2];
  const float* tg=(const float*)d_in[3];
  const float* priors=(const float*)d_in[4];
  int nt = in_sizes[3]/6;
  if(nt>NT_MAX) nt=NT_MAX;
  if(nt<1) nt=1;

  char* ws=(char*)d_ws;
  float*    ovr    =(float*)   (ws+O_OVR);
  int*      gix    =(int*)     (ws+O_GIX);
  float*    objc   =(float*)   (ws+O_OBJ);
  float*    lsc    =(float*)   (ws+O_LSC);
  float*    bcearr =(float*)   (ws+O_BCE);
  int*      list   =(int*)     (ws+O_LST);
  int*      lj     =(int*)     (ws+O_LJ);
  int*      cnt    =(int*)     (ws+O_CNT);
  unsigned long long* bpp=(unsigned long long*)(ws+O_BPP);
  float4*   partA  =(float4*)  (ws+O_PA);
  int*      partN  =(int*)     (ws+O_PN);
  float2*   part2  =(float2*)  (ws+O_P2);
  int*      binlist=(int*)     (ws+O_BINL);
  unsigned* histA  =(unsigned*)(ws+O_HA);
  unsigned* histB  =(unsigned*)(ws+O_HB);
  float*    accf   =(float*)   (ws+O_ACC);
  int*      acci   =(int*)     (ws+O_ACCI);
  unsigned* zbase  =(unsigned*)(ws+O_HA);

  int ntb=(nt+255)/256;
  k_init<<<ZBLK+ntb,256,0,stream>>>(tg,nt,list,cnt,lj,zbase);
  k_big1<<<2*NBLK_MAIN+nt*NCH,256,0,stream>>>(f0,f1,f2,tg,priors,list,cnt,nt,ovr,gix,objc,bpp);
  k_bpsc<<<1,256,0,stream>>>(tg,nt,bpp,lj,ovr);
  dim3 gm(GX_MAIN, NB);
  k_lc<<<gm,256,0,stream>>>(tg,objc,ovr,gix,nt,lsc,bcearr,histA,partN);
  k_redscanA<<<NB,256,0,stream>>>(partN,histA,acci);
  k_big2<<<2*NBLK_MAIN,256,0,stream>>>(f0,f1,f2,tg,priors,ovr,gix,lsc,bcearr,acci,nt,histB,partA);
  k_select<<<gm,256,0,stream>>>(lsc,bcearr,histB,acci,part2,binlist);
  k_ties<<<NB,256,0,stream>>>(bcearr,acci,accf,binlist,histB);
  k_final<<<1,256,0,stream>>>(partA,part2,accf,acci,(float*)d_out);
}

// Round 13
// 132.877 us; speedup vs baseline: 3.7600x; 1.0411x over previous
//
#include <hip/hip_runtime.h>
#include <math.h>

#define MTOT 42000
#define NB 8
#define NCLS 80
#define CAP_LIST 4096
#define MAXT 256
#define NT_MAX 2048
#define GX_MAIN 165                 // ceil(42000/256)
#define NBLK_MAIN (GX_MAIN*NB)      // 1320
#define NCHB 8                      // bestprior chunks per target
#define CSB 5250                    // 42000/8
#define TCH 512                     // match target-staging chunk

// ---- workspace byte offsets ----
#define O_OVR 0
#define O_GIX (O_OVR + NB*MTOT*4)
#define O_OBJ (O_GIX + NB*MTOT*4)        // compact obj channel [NB][MTOT]
#define O_LSC (O_OBJ + NB*MTOT*4)
#define O_BCE (O_LSC + NB*MTOT*4)
#define O_LJ  (O_BCE + NB*MTOT*4)
#define O_BPP (((O_LJ + NT_MAX*4 + 7)/8)*8)  // u64 partials [NT_MAX][NCHB]
#define O_PA  (O_BPP + NT_MAX*NCHB*8)    // posloss float4 partials [NBLK_MAIN]
#define O_PN  (O_PA + NBLK_MAIN*16)      // k_lc int partials [NBLK_MAIN]
#define O_P2  (O_PN + NBLK_MAIN*4)       // k_select float2 partials [NBLK_MAIN]
#define O_BINL (O_P2 + NBLK_MAIN*8)      // tie list [NB][CAP_LIST][2]
// kernel-zeroed region:
#define O_HA  (((O_BINL + NB*CAP_LIST*2*4 + 255)/256)*256)
#define O_HB  (O_HA + NB*256*4)
#define O_ACC (O_HB + NB*256*4)          // accf[0..15]: [5]=tie bce sum
#define O_ACCI (O_ACC + 64)              // acci[0..31]
#define O_ZEND (O_ACCI + 128)
#define ZWORDS ((O_ZEND - O_HA)/4)
#define ZBLK ((ZWORDS + 255)/256)
// acci: [0]=num_pos [1]=tie negsel cnt [2..9]=coarse ca [10..17]=kres [18..25]=tie listn

__device__ __forceinline__ float iou_cxcywh(float acx,float acy,float aw,float ah,
                                            float bcx,float bcy,float bw,float bh){
  float ax0=acx-aw*0.5f, ay0=acy-ah*0.5f, ax1=acx+aw*0.5f, ay1=acy+ah*0.5f;
  float bx0=bcx-bw*0.5f, by0=bcy-bh*0.5f, bx1=bcx+bw*0.5f, by1=bcy+bh*0.5f;
  float tlx=fmaxf(ax0,bx0), tly=fmaxf(ay0,by0);
  float brx=fminf(ax1,bx1), bry=fminf(ay1,by1);
  float wx=fmaxf(brx-tlx,0.f), wy=fmaxf(bry-tly,0.f);
  float inter=wx*wy;
  return inter/(aw*ah+bw*bh-inter+1e-9f);
}

__device__ __forceinline__ float sl1(float x){
  float ax=fabsf(x); return ax<1.f ? 0.5f*ax*ax : ax-0.5f;
}

__device__ __forceinline__ void feat_base(const float* f0,const float* f1,const float* f2,
                                          int i,int m,const float** basep,int* hwp){
  const float* fp; int hw, loc;
  if(m<32000){ fp=f0; hw=6400; loc=m; }
  else if(m<40000){ fp=f1; hw=1600; loc=m-32000; }
  else { fp=f2; hw=400; loc=m-40000; }
  int a=loc/hw, p=loc-a*hw;
  *basep = fp + (size_t)(i*425 + a*85)*(size_t)hw + p;
  *hwp = hw;
}

// inline fine-scan: 16-bit boundary bin + residual
__device__ __forceinline__ void fine_scan(const unsigned* hb,int ca,int kres,int* bs_out,int* r_out){
  if(ca==0x7fffffff){ *bs_out=0x7fffffff; *r_out=0; return; }
  int run=0, bs=-1, r=0;
  for(int f=255;f>=0;f--){
    int cb=(int)hb[f];
    if(run<kres && run+cb>=kres){ bs=(ca<<8)|f; r=kres-run; break; }
    run+=cb;
  }
  if(bs<0){ bs=(ca<<8); r=kres-run; }
  *bs_out=bs; *r_out=r;
}

// mega horizontal fusion: zero | lj-prep | match(self-filter) | obj prefetch | bpA
// [0,ZBLK) | [ZBLK,b0) | [b0,b1) | [b1,b2) | [b2,b2+nt*NCHB)
__global__ void k_big0(const float* __restrict__ f0,const float* __restrict__ f1,const float* __restrict__ f2,
                       const float* __restrict__ tg,const float* __restrict__ priors,
                       int nt,int b0,int b1,int b2,
                       int* __restrict__ lj,unsigned* __restrict__ zbase,
                       float* __restrict__ ovr,int* __restrict__ gix,
                       float* __restrict__ objc,unsigned long long* __restrict__ bpp){
  __shared__ float st[TCH*6];
  __shared__ unsigned long long su[256];
  int b=blockIdx.x, tid=threadIdx.x;
  if(b<ZBLK){
    int w=b*256+tid;
    if(w<ZWORDS) zbase[w]=0u;
    return;
  }
  if(b<b0){
    // lj-prep: rank of target within its image
    int t=(b-ZBLK)*256+tid;
    if(t>=nt) return;
    int img=(int)tg[t*6];
    int j=0;
    for(int q=0;q<t;q++) if((int)tg[q*6]==img) j++;
    lj[t]=j;
    return;
  }
  if(b<b1){
    // ---- match: per (image i, 256-col block), self-filtering over all nt targets ----
    int idx=b-b0;
    int i=idx/GX_MAIN, cb=idx-(idx/GX_MAIN)*GX_MAIN;
    int m=cb*256+tid;
    bool valid=(m<MTOT);
    float4 pr=make_float4(0.f,0.f,1.f,1.f);
    if(valid) pr=((const float4*)priors)[m];
    float maxv=-1.f; int bi=0;
    for(int base=0;base<nt;base+=TCH){
      int nch=min(TCH,nt-base);
      for(int j=tid;j<nch;j+=256){
        #pragma unroll
        for(int q=0;q<6;q++) st[j*6+q]=tg[(base+j)*6+q];
      }
      __syncthreads();
      if(valid){
        for(int j=0;j<nch;j++){
          if((int)st[j*6]!=i) continue;
          float v=iou_cxcywh(st[j*6+2],st[j*6+3],st[j*6+4],st[j*6+5],pr.x,pr.y,pr.z,pr.w);
          if(v>maxv){ maxv=v; bi=base+j; }
        }
      }
      __syncthreads();
    }
    if(valid){ ovr[i*MTOT+m]=maxv; gix[i*MTOT+m]=bi; }
  } else if(b<b2){
    // ---- obj channel prefetch into compact array ----
    int idx=b-b1;
    int i=idx/GX_MAIN, cb=idx-(idx/GX_MAIN)*GX_MAIN;
    int m=cb*256+tid;
    if(m>=MTOT) return;
    const float* base; int hw;
    feat_base(f0,f1,f2,i,m,&base,&hw);
    objc[i*MTOT+m]=base[(size_t)4*hw];
  } else {
    // ---- bpA: chunked best-prior partials (8 chunks/target) ----
    int idx=b-b2;
    int t=idx/NCHB, c=idx-(idx/NCHB)*NCHB;
    float acx=tg[t*6+2],acy=tg[t*6+3],aw=tg[t*6+4],ah=tg[t*6+5];
    int m0=c*CSB, m1=min(m0+CSB,MTOT);
    float bv=-1.f; int bm=0;
    for(int m=m0+tid;m<m1;m+=256){
      float4 pr=((const float4*)priors)[m];
      float v=iou_cxcywh(acx,acy,aw,ah,pr.x,pr.y,pr.z,pr.w);
      if(v>bv){ bv=v; bm=m; }
    }
    unsigned long long p=(bv<0.f)?0ull
        :(((unsigned long long)__float_as_uint(bv))<<32)|(unsigned)(~bm);
    su[tid]=p;
    __syncthreads();
    for(int o=128;o>0;o>>=1){
      if(tid<o){ if(su[tid+o]>su[tid]) su[tid]=su[tid+o]; }
      __syncthreads();
    }
    if(tid==0) bpp[(size_t)t*NCHB+c]=su[0];
  }
}

// bpB + forced-prior scatter, single block (tiny)
__global__ void k_bpsc(const float* __restrict__ tg,int nt,
                       const unsigned long long* __restrict__ bpp,
                       const int* __restrict__ lj,float* __restrict__ ovr){
  __shared__ int tbp[NT_MAX];
  __shared__ int timg[NT_MAX];
  int tid=threadIdx.x;
  for(int t=tid;t<nt;t+=256){
    unsigned long long best=0ull;
    const unsigned long long* pp=&bpp[(size_t)t*NCHB];
    #pragma unroll
    for(int c=0;c<NCHB;c++){ unsigned long long v=pp[c]; if(v>best) best=v; }
    int bm=~((unsigned)(best&0xFFFFFFFFull));
    tbp[t]=min(max(bm,0),MTOT-1);
    timg[t]=(int)tg[t*6];
  }
  __syncthreads();
  for(int t=tid;t<nt;t+=256){
    int img=timg[t];
    if(img<0||img>=NB) continue;
    int myp=tbp[t];
    bool last=true;
    for(int q=t+1;q<nt;q++) if(timg[q]==img&&tbp[q]==myp){ last=false; break; }
    if(last) ovr[img*MTOT+myp]=(float)lj[t];
  }
}

// lc/bce from compact obj (contiguous), coarse hist, npos partials
__global__ void k_lc(const float* __restrict__ tg,const float* __restrict__ objc,
                     const float* __restrict__ ovr,const int* __restrict__ gix,int nt,
                     float* __restrict__ lsc,float* __restrict__ bcearr,
                     unsigned* __restrict__ histA,int* __restrict__ partN){
  __shared__ unsigned h[256];
  __shared__ int snp[4];
  int tid=threadIdx.x, lane=tid&63, wid=tid>>6;
  h[tid]=0u;
  __syncthreads();
  int i=blockIdx.y;
  int m=blockIdx.x*256+tid;
  int npos=0;
  if(m<MTOT){
    int gid=i*MTOT+m;
    float ov=ovr[gid];
    int gi=min(max(gix[gid],0),nt-1);
    float tc=tg[gi*6+1]+1.f;
    bool pos=(ov>=0.5f)&&(tc>0.f);
    float obj=objc[gid];
    float sp=log1pf(expf(-fabsf(obj)));
    float bce=fmaxf(obj,0.f)-(pos?obj:0.f)+sp;
    float lc=pos?0.f:(fmaxf(-obj,0.f)+sp);
    lsc[gid]=lc; bcearr[gid]=bce;
    atomicAdd(&h[__float_as_uint(lc)>>24],1u);
    npos=pos?1:0;
  }
  #pragma unroll
  for(int o=32;o>0;o>>=1) npos+=__shfl_xor(npos,o);
  if(lane==0) snp[wid]=npos;
  __syncthreads();
  unsigned hc=h[tid];
  if(hc) atomicAdd(&histA[i*256+tid],hc);
  if(tid==0) partN[blockIdx.y*GX_MAIN+blockIdx.x]=snp[0]+snp[1]+snp[2]+snp[3];
}

// np reduce + coarse scan (8 blocks)
__global__ void k_redscanA(const int* __restrict__ partN,const unsigned* __restrict__ histA,
                           int* __restrict__ acci){
  __shared__ int an[256];
  __shared__ unsigned h[256];
  int t=threadIdx.x, b=blockIdx.x;
  int n=0;
  for(int e=t;e<NBLK_MAIN;e+=256) n+=partN[e];
  an[t]=n;
  __syncthreads();
  for(int o=128;o>0;o>>=1){ if(t<o) an[t]+=an[t+o]; __syncthreads(); }
  int np=an[0];
  if(b==0&&t==0) acci[0]=np;
  h[t]=histA[b*256+t];
  __syncthreads();
  if(t==0){
    int kk=min(np,MTOT-np);
    if(kk<=0){ acci[2+b]=0x7fffffff; acci[10+b]=0; }
    else{
      int run=0, ca=-1, kres=0;
      for(int c2=255;c2>=0;c2--){
        int cbn=(int)h[c2];
        if(run<kk&&run+cbn>=kk){ ca=c2; kres=kk-run; break; }
        run+=cbn;
      }
      if(ca<0){ ca=0; kres=kk-run; }
      acci[2+b]=ca; acci[10+b]=kres;
    }
  }
}

// horizontal fusion: [0,1320) fine hist | [1320,2640) positive box+CE losses
__global__ void k_big2(const float* __restrict__ f0,const float* __restrict__ f1,const float* __restrict__ f2,
                       const float* __restrict__ tg,const float* __restrict__ priors,
                       const float* __restrict__ ovr,const int* __restrict__ gix,
                       const float* __restrict__ lsc,const float* __restrict__ bcearr,
                       const int* __restrict__ acci,int nt,
                       unsigned* __restrict__ histB,float4* __restrict__ partA){
  __shared__ unsigned h[256];
  __shared__ float rA[4],rB[4],rC[4],rD[4];
  int b=blockIdx.x, tid=threadIdx.x, lane=tid&63, wid=tid>>6;
  if(b<NBLK_MAIN){
    h[tid]=0u;
    __syncthreads();
    int i=b/GX_MAIN, cb=b-(b/GX_MAIN)*GX_MAIN;
    int ca=acci[2+i];
    int m=cb*256+tid;
    if(m<MTOT && ca!=0x7fffffff){
      unsigned u=__float_as_uint(lsc[i*MTOT+m]);
      if((int)(u>>24)==ca) atomicAdd(&h[(u>>16)&0xFF],1u);
    }
    __syncthreads();
    unsigned c=h[tid];
    if(c) atomicAdd(&histB[i*256+tid],c);
  } else {
    int idx=b-NBLK_MAIN;
    int i=idx/GX_MAIN, cb=idx-(idx/GX_MAIN)*GX_MAIN;
    int m=cb*256+tid;
    bool valid=(m<MTOT);
    float lxy=0.f,lwh=0.f,bcep=0.f,wce=0.f;
    bool pos=false; int gi=0;
    if(valid){
      int gid=i*MTOT+m;
      float ov=ovr[gid];
      gi=min(max(gix[gid],0),nt-1);
      float tc=tg[gi*6+1]+1.f;
      pos=(ov>=0.5f)&&(tc>0.f);
      if(pos){
        const float* base; int hw;
        feat_base(f0,f1,f2,i,m,&base,&hw);
        bcep=bcearr[gid];
        float4 pr=((const float4*)priors)[m];
        float bx=tg[gi*6+2],by=tg[gi*6+3],bw=tg[gi*6+4],bh=tg[gi*6+5];
        float tx=(bx-pr.x)/pr.z, ty=(by-pr.y)/pr.w;
        float tw=logf(bw/pr.z), th=logf(bh/pr.w);
        lxy=sl1(base[0]-tx)+sl1(base[(size_t)hw]-ty);
        lwh=sl1(base[(size_t)2*hw]-tw)+sl1(base[(size_t)3*hw]-th);
      }
    }
    unsigned long long mask=__ballot(valid&&pos);
    while(mask){
      int s=__ffsll(mask)-1;
      mask&=mask-1;
      int m_s=__shfl(m,s);
      int gi_s=__shfl(gi,s);
      const float* bs2; int hws;
      feat_base(f0,f1,f2,i,m_s,&bs2,&hws);
      int label=(int)(tg[gi_s*6+1]+1.f)-1;
      label=min(NCLS-1,max(0,label));
      float v0=bs2[(size_t)(5+lane)*hws];
      float v1=(lane<16)?bs2[(size_t)(69+lane)*hws]:-3.0e38f;
      float mx=fmaxf(v0,v1);
      #pragma unroll
      for(int o=32;o>0;o>>=1) mx=fmaxf(mx,__shfl_xor(mx,o));
      float se=expf(v0-mx)+((lane<16)?expf(v1-mx):0.f);
      float xl=((lane==label)?v0:0.f)+((lane<16&&lane+64==label)?v1:0.f);
      #pragma unroll
      for(int o=32;o>0;o>>=1){ se+=__shfl_xor(se,o); xl+=__shfl_xor(xl,o); }
      wce+=logf(se)+mx-xl;
    }
    #pragma unroll
    for(int o=32;o>0;o>>=1){
      lxy+=__shfl_xor(lxy,o); lwh+=__shfl_xor(lwh,o); bcep+=__shfl_xor(bcep,o);
    }
    if(lane==0){ rA[wid]=lxy; rB[wid]=lwh; rC[wid]=wce; rD[wid]=bcep; }
    __syncthreads();
    if(tid==0)
      partA[idx]=make_float4(rA[0]+rA[1]+rA[2]+rA[3], rB[0]+rB[1]+rB[2]+rB[3],
                             rC[0]+rC[1]+rC[2]+rC[3], rD[0]+rD[1]+rD[2]+rD[3]);
  }
}

// select negatives above 16-bit threshold (fine_scan locally); partials + tie list
__global__ void k_select(const float* __restrict__ lsc,const float* __restrict__ bcearr,
                         const unsigned* __restrict__ histB,
                         int* __restrict__ acci,float2* __restrict__ part2,
                         int* __restrict__ binlist){
  __shared__ unsigned hb[256];
  __shared__ int sbs;
  __shared__ float ss[4]; __shared__ float sc[4];
  int tid=threadIdx.x, lane=tid&63, wid=tid>>6;
  int i=blockIdx.y;
  int ca=acci[2+i], kres=acci[10+i];
  hb[tid]=(ca==0x7fffffff)?0u:histB[i*256+tid];
  __syncthreads();
  if(tid==0){ int bs,r; fine_scan(hb,ca,kres,&bs,&r); sbs=bs; }
  __syncthreads();
  int bs_=sbs;
  int m=blockIdx.x*256+tid;
  float s=0.f, c=0.f;
  if(m<MTOT){
    int gid=i*MTOT+m;
    unsigned u=__float_as_uint(lsc[gid]);
    int bin=(int)(u>>16);
    if(bin>bs_){ s=bcearr[gid]; c=1.f; }
    else if(bin==bs_){
      int idx=atomicAdd(&acci[18+i],1);
      if(idx<CAP_LIST){
        binlist[((size_t)i*CAP_LIST+idx)*2  ]=(int)u;
        binlist[((size_t)i*CAP_LIST+idx)*2+1]=gid;
      }
    }
  }
  #pragma unroll
  for(int o=32;o>0;o>>=1){ s+=__shfl_xor(s,o); c+=__shfl_xor(c,o); }
  if(lane==0){ ss[wid]=s; sc[wid]=c; }
  __syncthreads();
  if(tid==0) part2[blockIdx.y*gridDim.x+blockIdx.x]=make_float2(ss[0]+ss[1]+ss[2]+ss[3], sc[0]+sc[1]+sc[2]+sc[3]);
}

// stable tie-resolution, one block per image; tie list staged in LDS
#define TSTAGE 2048
__global__ void k_ties(const float* __restrict__ bcearr,int* __restrict__ acci,
                       float* __restrict__ accf,const int* __restrict__ binlist,
                       const unsigned* __restrict__ histB){
  __shared__ unsigned hb[256];
  __shared__ int sbs, sr;
  __shared__ int sl[TSTAGE*2];
  int i=blockIdx.x, tid=threadIdx.x;
  int ca=acci[2+i], kres=acci[10+i];
  hb[tid]=(ca==0x7fffffff)?0u:histB[i*256+tid];
  __syncthreads();
  if(tid==0){ int bs,r; fine_scan(hb,ca,kres,&bs,&r); sbs=bs; sr=r; }
  __syncthreads();
  if(sbs==0x7fffffff) return;
  int n=min(acci[18+i],CAP_LIST);
  int nstage=min(n,TSTAGE);
  for(int e=tid;e<nstage;e+=256){
    sl[e*2  ]=binlist[((size_t)i*CAP_LIST+e)*2  ];
    sl[e*2+1]=binlist[((size_t)i*CAP_LIST+e)*2+1];
  }
  __syncthreads();
  int r=sr;
  for(int e=tid;e<n;e+=blockDim.x){
    unsigned ue; int ge;
    if(e<nstage){ ue=(unsigned)sl[e*2]; ge=sl[e*2+1]; }
    else{ ue=(unsigned)binlist[((size_t)i*CAP_LIST+e)*2]; ge=binlist[((size_t)i*CAP_LIST+e)*2+1]; }
    int rank=0;
    for(int q=0;q<n;q++){
      unsigned uq; int gq;
      if(q<nstage){ uq=(unsigned)sl[q*2]; gq=sl[q*2+1]; }
      else{ uq=(unsigned)binlist[((size_t)i*CAP_LIST+q)*2]; gq=binlist[((size_t)i*CAP_LIST+q)*2+1]; }
      rank += ((uq>ue)||(uq==ue&&gq<ge))?1:0;
    }
    if(rank<r){
      atomicAdd(&accf[5], bcearr[ge]);
      atomicAdd(&acci[1], 1);
    }
  }
}

// final: reduce partA/part2 + combine (1 block)
__global__ void k_final(const float4* __restrict__ partA,const float2* __restrict__ part2,
                        const float* __restrict__ accf,const int* __restrict__ acci,
                        float* __restrict__ out){
  __shared__ float a0[256],a1[256],a2[256],a3[256],s0[256],s1[256];
  int tid=threadIdx.x;
  float x=0,y=0,z=0,w=0,ns=0,nc=0;
  for(int e=tid;e<NBLK_MAIN;e+=256){
    float4 p=partA[e]; x+=p.x; y+=p.y; z+=p.z; w+=p.w;
    float2 q=part2[e]; ns+=q.x; nc+=q.y;
  }
  a0[tid]=x; a1[tid]=y; a2[tid]=z; a3[tid]=w; s0[tid]=ns; s1[tid]=nc;
  __syncthreads();
  for(int o=128;o>0;o>>=1){
    if(tid<o){
      a0[tid]+=a0[tid+o]; a1[tid]+=a1[tid+o]; a2[tid]+=a2[tid+o]; a3[tid]+=a3[tid+o];
      s0[tid]+=s0[tid+o]; s1[tid]+=s1[tid+o];
    }
    __syncthreads();
  }
  if(tid==0){
    float negsum=s0[0]+accf[5];
    float negcnt=s1[0]+(float)acci[1];
    int np=acci[0];
    float npf=(float)np;
    float den2=fmaxf(2.f*npf,1.f);
    float lbox=a0[0]/den2+a1[0]/den2;
    float lcls=a2[0]/fmaxf(npf,1.f);
    float selc=npf+negcnt;
    float lobj=(a3[0]+negsum)/fmaxf(selc,1.f);
    out[0]=lbox+lcls+lobj;
    out[1]=lbox;
    out[2]=lobj;
    out[3]=lcls;
  }
}

extern "C" void kernel_launch(void* const* d_in, const int* in_sizes, int n_in,
                              void* d_out, int out_size, void* d_ws, size_t ws_size,
                              hipStream_t stream) {
  const float* f0=(const float*)d_in[0];
  const float* f1=(const float*)d_in[1];
  const float* f2=(const float*)d_in[2];
  const float* tg=(const float*)d_in[3];
  const float* priors=(const float*)d_in[4];
  int nt = in_sizes[3]/6;
  if(nt>NT_MAX) nt=NT_MAX;
  if(nt<1) nt=1;

  char* ws=(char*)d_ws;
  float*    ovr    =(float*)   (ws+O_OVR);
  int*      gix    =(int*)     (ws+O_GIX);
  float*    objc   =(float*)   (ws+O_OBJ);
  float*    lsc    =(float*)   (ws+O_LSC);
  float*    bcearr =(float*)   (ws+O_BCE);
  int*      lj     =(int*)     (ws+O_LJ);
  unsigned long long* bpp=(unsigned long long*)(ws+O_BPP);
  float4*   partA  =(float4*)  (ws+O_PA);
  int*      partN  =(int*)     (ws+O_PN);
  float2*   part2  =(float2*)  (ws+O_P2);
  int*      binlist=(int*)     (ws+O_BINL);
  unsigned* histA  =(unsigned*)(ws+O_HA);
  unsigned* histB  =(unsigned*)(ws+O_HB);
  float*    accf   =(float*)   (ws+O_ACC);
  int*      acci   =(int*)     (ws+O_ACCI);
  unsigned* zbase  =(unsigned*)(ws+O_HA);

  int ntb=(nt+255)/256;
  int b0=ZBLK+ntb, b1=b0+NBLK_MAIN, b2=b1+NBLK_MAIN;
  k_big0<<<b2+nt*NCHB,256,0,stream>>>(f0,f1,f2,tg,priors,nt,b0,b1,b2,lj,zbase,ovr,gix,objc,bpp);
  k_bpsc<<<1,256,0,stream>>>(tg,nt,bpp,lj,ovr);
  dim3 gm(GX_MAIN, NB);
  k_lc<<<gm,256,0,stream>>>(tg,objc,ovr,gix,nt,lsc,bcearr,histA,partN);
  k_redscanA<<<NB,256,0,stream>>>(partN,histA,acci);
  k_big2<<<2*NBLK_MAIN,256,0,stream>>>(f0,f1,f2,tg,priors,ovr,gix,lsc,bcearr,acci,nt,histB,partA);
  k_select<<<gm,256,0,stream>>>(lsc,bcearr,histB,acci,part2,binlist);
  k_ties<<<NB,256,0,stream>>>(bcearr,acci,accf,binlist,histB);
  k_final<<<1,256,0,stream>>>(partA,part2,accf,acci,(float*)d_out);
}